// Round 7
// baseline (192.341 us; speedup 1.0000x reference)
//
#include <hip/hip_runtime.h>
#include <hip/hip_bf16.h>

// B=8, N=2048, DX=1024, DK=DV=128. Inputs fp32, output fp32.
// out = softmax(K V^T / sqrt(128)) V, K = x Wk^T + bk, V = x Wv^T + bv.
// R15b: resubmit of R15 (infra failure, no data). Flash phase-diversity
//      restructure: 32q/block, 2 waves, KVBLK=32, 36.4KB LDS -> 4 independent
//      blocks/CU (was 2 barrier-locked blocks). Per-wave dataflow identical
//      to R13 (verified): reg-K, wave-private sP, counted vmcnt(8),
//      K pre-scaled. kv_gemm/wconv/combine = R13 (verified).

typedef short s16x8 __attribute__((ext_vector_type(8)));
typedef float f32x4 __attribute__((ext_vector_type(4)));
typedef unsigned short u16;

#define AS1 __attribute__((address_space(1)))
#define AS3 __attribute__((address_space(3)))

__device__ __forceinline__ void gld_lds16(const void* g, void* l) {
  // async global->LDS: per-lane gather, lands at wave-uniform base + lane*16
  __builtin_amdgcn_global_load_lds((const AS1 unsigned int*)g, (AS3 unsigned int*)l, 16, 0, 0);
}

__device__ __forceinline__ float bf2f(u16 u) {
  unsigned int v = ((unsigned int)u) << 16;
  return __builtin_bit_cast(float, v);
}
__device__ __forceinline__ u16 f2bf(float f) {
  unsigned int u = __builtin_bit_cast(unsigned int, f);
  u += 0x7fffu + ((u >> 16) & 1u);   // RNE
  return (u16)(u >> 16);
}
__device__ __forceinline__ unsigned pack_bf2(float a, float b) {
  unsigned ua = __builtin_bit_cast(unsigned, a) + 0x8000u;
  unsigned ub = __builtin_bit_cast(unsigned, b) + 0x8000u;
  return __builtin_amdgcn_perm(ub, ua, 0x07060302u);
}

// ---------------- Kernel W: weights fp32 -> bf16 (wk||wv -> wbf[256][1024]) --
__global__ __launch_bounds__(256, 4) void wconv_kernel(
    const float* __restrict__ wk, const float* __restrict__ wv,
    u16* __restrict__ wbf)
{
  const int e = (blockIdx.x * 256 + threadIdx.x) * 8;
  const float* src = (e < 131072) ? (wk + e) : (wv + (e - 131072));
  float4 a = *(const float4*)src;
  float4 b = *(const float4*)(src + 4);
  union { unsigned u[4]; s16x8 v; } pk;
  pk.u[0] = pack_bf2(a.x, a.y); pk.u[1] = pack_bf2(a.z, a.w);
  pk.u[2] = pack_bf2(b.x, b.y); pk.u[3] = pack_bf2(b.z, b.w);
  *(s16x8*)(wbf + e) = pk.v;
}

// ---------------- Kernel A: fused K|V projection GEMM (+ V^T emit) -----------
// grid 256, 512 threads: block = 64 rows x 256 cols. BK=64, 16 steps.
// Wave w: rows (w>>2)*32..+31, cols (w&3)*64..+63 (w&3 0-1: K, 2-3: V).
// B prefetch 2 steps deep into 4 LDS buffers; raw barrier + vmcnt(6) so
// in-flight DMAs are never drained at the barrier. A regs 2 steps deep.
// K output pre-scaled by 1/sqrt(128) so flash softmax is __expf(sacc).
__global__ __launch_bounds__(512, 2) void kv_gemm_kernel(
    const float* __restrict__ x, const u16* __restrict__ wbf,
    const float* __restrict__ bk, const float* __restrict__ bv,
    u16* __restrict__ Kout, u16* __restrict__ Vout, u16* __restrict__ VTout)
{
  __shared__ u16 sA[2][8 * 512];     // 2 x 8 KB  [slice=grb*2+ks][lane][8]
  __shared__ u16 sB[4][32 * 512];    // 4 x 32 KB [slice=gcb*2+ks][lane][8]

  const int tid  = threadIdx.x;
  const int wave = tid >> 6;
  const int lane = tid & 63;
  const int l16  = lane & 15;
  const int lq   = lane >> 4;
  const int row0 = blockIdx.x * 64;
  const int wr   = wave >> 2;        // row half 0..1
  const int wc   = wave & 3;         // col group 0..3

  f32x4 acc[2][4];
  for (int i = 0; i < 2; ++i)
    for (int j = 0; j < 4; ++j) acc[i][j] = (f32x4){0.f, 0.f, 0.f, 0.f};

  // A: thread stages chunk: kc=tid&7 (k-chunk of 8 floats), arow=tid>>3 (0..63)
  const int kc = tid & 7, arow = tid >> 3;
  const float* aSrc = x + (size_t)(row0 + arow) * 1024 + kc * 8;
  const int aSlot = (((arow >> 4) * 2 + (kc >> 2)) * 512) + ((kc & 3) * 16 + (arow & 15)) * 8;

  // B: 4 chunks/thread; chunk i -> slice sl = wave + i*8 (gcb=sl>>1, ks=sl&1)
  const u16* bSrc[4];
  for (int i = 0; i < 4; ++i) {
    const int sl = wave + i * 8;
    bSrc[i] = wbf + (size_t)((sl >> 1) * 16 + l16) * 1024 + (sl & 1) * 32 + lq * 8;
  }

  // prologue: B(0)->buf0, B(1)->buf1 in flight; A regs 2 steps deep
  for (int i = 0; i < 4; ++i)
    gld_lds16(bSrc[i], &sB[0][(wave + i * 8) * 512]);
  float4 p0a = *(const float4*)(aSrc);
  float4 p0b = *(const float4*)(aSrc + 4);
  for (int i = 0; i < 4; ++i)
    gld_lds16(bSrc[i] + 64, &sB[1][(wave + i * 8) * 512]);
  float4 p1a = *(const float4*)(aSrc + 64);
  float4 p1b = *(const float4*)(aSrc + 68);

#pragma unroll
  for (int s = 0; s < 16; ++s) {
    const int buf2 = s & 1, buf4 = s & 3;
    // pack A(s) -> sA[buf2]  (reg dep makes compiler wait for A(s) loads)
    {
      union { unsigned u[4]; s16x8 v; } pk;
      pk.u[0] = pack_bf2(p0a.x, p0a.y); pk.u[1] = pack_bf2(p0a.z, p0a.w);
      pk.u[2] = pack_bf2(p0b.x, p0b.y); pk.u[3] = pack_bf2(p0b.z, p0b.w);
      *(s16x8*)(&sA[buf2][aSlot]) = pk.v;
    }
    asm volatile("s_waitcnt lgkmcnt(0)" ::: "memory");  // own LDS writes visible
    __builtin_amdgcn_s_barrier();
    // counted drain: each iter issues exactly 6 VMEM (4 gld_lds + 2 A-loads),
    // so vmcnt(6) retires everything from iter s-2 and older => B(s) landed,
    // while B(s+1)+A(s+1) stay in flight across the barrier. Last iter: 0.
    if (s == 15) asm volatile("s_waitcnt vmcnt(0)" ::: "memory");
    else         asm volatile("s_waitcnt vmcnt(6)" ::: "memory");
    __builtin_amdgcn_sched_barrier(0);

    if (s + 2 < 16) {   // B(s+2) flies for the next two compute phases
      for (int i = 0; i < 4; ++i)
        gld_lds16(bSrc[i] + (s + 2) * 64, &sB[(s + 2) & 3][(wave + i * 8) * 512]);
    }
    // rotate A pipeline: consume p0 (packed above), load A(s+2)
    p0a = p1a; p0b = p1b;
    if (s + 2 < 16) {
      p1a = *(const float4*)(aSrc + (s + 2) * 64);
      p1b = *(const float4*)(aSrc + (s + 2) * 64 + 4);
    }

    s16x8 af[2][2], bfr[4][2];
    for (int rb = 0; rb < 2; ++rb)
      for (int ks = 0; ks < 2; ++ks)
        af[rb][ks] = *(const s16x8*)(&sA[buf2][(((wr * 2 + rb) * 2 + ks) * 64 + lane) * 8]);
    for (int cb = 0; cb < 4; ++cb)
      for (int ks = 0; ks < 2; ++ks)
        bfr[cb][ks] = *(const s16x8*)(&sB[buf4][(((wc * 4 + cb) * 2 + ks) * 64 + lane) * 8]);
    for (int rb = 0; rb < 2; ++rb)
      for (int cb = 0; cb < 4; ++cb)
        for (int ks = 0; ks < 2; ++ks)
          acc[rb][cb] = __builtin_amdgcn_mfma_f32_16x16x32_bf16(af[rb][ks], bfr[cb][ks], acc[rb][cb], 0, 0, 0);
  }

  const int  colBase = wc * 64;
  const bool isV = (wc >= 2);
  const float vscale = isV ? 1.0f : 0.08838834764831845f;   // 1/sqrt(128) folded into K
  u16* outN = isV ? Vout : Kout;
  float fbias[4];
  for (int cb = 0; cb < 4; ++cb) {
    const int col = colBase + cb * 16 + l16;
    fbias[cb] = isV ? bv[col - 128] : bk[col];
  }
  for (int rb = 0; rb < 2; ++rb) {
    const int grow0 = row0 + wr * 32 + rb * 16 + lq * 4;
    for (int cb = 0; cb < 4; ++cb) {
      const int gcol = colBase + cb * 16 + l16;
      const int ocol = isV ? (gcol - 128) : gcol;
      union { u16 u[4]; unsigned long long ull; } pk;
      for (int r = 0; r < 4; ++r) {
        u16 h = f2bf((acc[rb][cb][r] + fbias[cb]) * vscale);
        outN[(size_t)(grow0 + r) * 128 + ocol] = h;
        pk.u[r] = h;
      }
      if (isV) {
        const int bidx = grow0 >> 11;
        const int n    = grow0 & 2047;
        *(unsigned long long*)(VTout + (size_t)bidx * 128 * 2048 + (size_t)ocol * 2048 + n) = pk.ull;
      }
    }
  }
}

// ---------------- Kernel B: flash attention (no-max softmax, reg-K, dbuf) ----
// grid (64, 8, nz): 32 q-rows/block, 2 waves; KV tiles of 32; 1 barrier/tile.
// 36.4KB LDS -> 4 independent blocks/CU (phase diversity). Counted vmcnt(8):
// stage(mt+1)'s 8 DMAs/wave stay in flight through this tile's compute.
__global__ __launch_bounds__(128, 2) void flash_kernel(
    const u16* __restrict__ Kmat, const u16* __restrict__ Vmat,
    const u16* __restrict__ VT, float* __restrict__ out,
    float* __restrict__ Opart, float* __restrict__ lbuf)
{
  __shared__ u16 sV[2][4096];        // 2 x 8 KB  [slice=t*4+ks][lane][8]
  __shared__ u16 sVT[2][4096];       // 2 x 8 KB  [slice=v][lane][8]
  __shared__ u16 sP[32 * 66];        // 4.1 KB, stride 66 (odd-bank), wave-private rows

  const int tid  = threadIdx.x;
  const int wave = tid >> 6;         // 0..1
  const int lane = tid & 63;
  const int l16  = lane & 15;
  const int lq   = lane >> 4;
  const int b    = blockIdx.y;
  const int q0   = blockIdx.x * 32;
  const int z    = blockIdx.z;
  const int ntiles = (2048 / gridDim.z) / 32;
  const int mstart = z * (2048 / gridDim.z);

  // K fragments -> registers (pre-scaled by 1/sqrt(128) at projection)
  s16x8 kf[4];
  {
    const u16* Kb = Kmat + ((size_t)b * 2048 + q0 + wave * 16 + l16) * 128 + lq * 8;
    for (int ks = 0; ks < 4; ++ks) kf[ks] = *(const s16x8*)(Kb + ks * 32);
  }

  // staging: wave stages sV slices {w,w+2,w+4,w+6} and sVT slices {w,w+2,w+4,w+6}
  // sV slice sl: lane -> V[m0 + (sl>>2)*16 + l16][(sl&3)*32 + lq*8]
  // sVT slice dt: lane -> VT[dt*16 + l16][m0 + lq*8]
  const u16* vSrc[4];  const u16* vtSrc[4];
  {
    const u16* Vb  = Vmat + (size_t)b * 2048 * 128;
    const u16* VTb = VT   + (size_t)b * 128 * 2048;
    for (int i = 0; i < 4; ++i) {
      const int sl = wave + i * 2;
      vSrc[i]  = Vb  + (size_t)((sl >> 2) * 16 + l16) * 128 + (sl & 3) * 32 + lq * 8;  // + m0*128
      vtSrc[i] = VTb + (size_t)(sl * 16 + l16) * 2048 + lq * 8;                        // + m0
    }
  }

  f32x4 oacc[8];
  for (int v = 0; v < 8; ++v) oacc[v] = (f32x4){0.f, 0.f, 0.f, 0.f};
  float lrow[4] = {0.f, 0.f, 0.f, 0.f};

  // prologue: stage tile 0 -> buf 0 (8 DMAs/wave)
  for (int i = 0; i < 4; ++i) {
    const int sl = wave + i * 2;
    gld_lds16(vSrc[i] + (size_t)mstart * 128, &sV[0][sl * 512]);
    gld_lds16(vtSrc[i] + mstart,              &sVT[0][sl * 512]);
  }

  for (int mt = 0; mt < ntiles; ++mt) {
    const int buf = mt & 1;
    asm volatile("s_barrier" ::: "memory");    // both waves done reading buf^1
    if (mt + 1 < ntiles) {                     // issue stage(mt+1) FIRST...
      const int m1 = mstart + (mt + 1) * 32;
      for (int i = 0; i < 4; ++i) {
        const int sl = wave + i * 2;
        gld_lds16(vSrc[i] + (size_t)m1 * 128, &sV[buf ^ 1][sl * 512]);
        gld_lds16(vtSrc[i] + m1,              &sVT[buf ^ 1][sl * 512]);
      }
      // ...then counted wait: 16 outstanding -> 8 => stage(mt) landed,
      // stage(mt+1)'s 8 stay in flight through this whole tile's compute.
      asm volatile("s_waitcnt vmcnt(8)" ::: "memory");
    } else {
      asm volatile("s_waitcnt vmcnt(0)" ::: "memory");
    }
    __builtin_amdgcn_sched_barrier(0);

    // S = K.V^T  [16q][32m]: t in 0..1 (8 ds_read, 8 MFMA)
    f32x4 sacc[2];
    sacc[0] = (f32x4){0.f, 0.f, 0.f, 0.f};
    sacc[1] = (f32x4){0.f, 0.f, 0.f, 0.f};
    for (int ks = 0; ks < 4; ++ks)
      for (int t = 0; t < 2; ++t)
        sacc[t] = __builtin_amdgcn_mfma_f32_16x16x32_bf16(
            kf[ks], *(const s16x8*)(&sV[buf][(t * 4 + ks) * 512 + lane * 8]), sacc[t], 0, 0, 0);

    // softmax without max-shift (logits bounded; scale pre-folded): p = exp(s)
    for (int r = 0; r < 4; ++r) {
      const int prow = (wave * 16 + lq * 4 + r) * 66;
      float rs = 0.f;
      for (int t = 0; t < 2; ++t) {
        float p = __expf(sacc[t][r]);
        u16 h = f2bf(p);
        sP[prow + t * 16 + l16] = h;
        rs += bf2f(h);                 // denominator matches bf16 numerator
      }
      lrow[r] += rs;
    }

    // O += P.V  [16q][32m]x[32m][128d]: 1 sP read + 8 sVT reads, 8 MFMA
    {
      s16x8 a = *(const s16x8*)(&sP[(wave * 16 + l16) * 66 + lq * 8]);
      for (int v = 0; v < 8; ++v)
        oacc[v] = __builtin_amdgcn_mfma_f32_16x16x32_bf16(
            a, *(const s16x8*)(&sVT[buf][v * 512 + lane * 8]), oacc[v], 0, 0, 0);
    }
  }

  // finish l: reduce partial sums over the 16 column-lanes
  for (int r = 0; r < 4; ++r) {
    lrow[r] += __shfl_xor(lrow[r], 1);
    lrow[r] += __shfl_xor(lrow[r], 2);
    lrow[r] += __shfl_xor(lrow[r], 4);
    lrow[r] += __shfl_xor(lrow[r], 8);
  }

  const size_t rowg = (size_t)b * 2048 + q0 + wave * 16;
  if (gridDim.z == 1) {
    for (int r = 0; r < 4; ++r) {
      const float inv = 1.f / lrow[r];
      for (int v = 0; v < 8; ++v)
        out[(rowg + lq * 4 + r) * 128 + v * 16 + l16] = oacc[v][r] * inv;
    }
  } else {
    float* Op = Opart + (size_t)z * 2097152;
    float* lp = lbuf + (size_t)z * 32768;
    for (int r = 0; r < 4; ++r)
      for (int v = 0; v < 8; ++v)
        Op[(rowg + lq * 4 + r) * 128 + v * 16 + l16] = oacc[v][r];
    if (l16 == 0)
      for (int r = 0; r < 4; ++r)
        lp[rowg + lq * 4 + r] = lrow[r];
  }
}

// ---------------- Kernel C: combine 2 KV-split partials ----------------------
__global__ __launch_bounds__(256, 4) void combine_kernel(
    const float* __restrict__ Opart, const float* __restrict__ lbuf,
    float* __restrict__ out)
{
  const int idx = blockIdx.x * 256 + threadIdx.x;    // float4 idx, 524288 total
  const int row = idx >> 5;
  const float4 o0 = ((const float4*)Opart)[idx];
  const float4 o1 = ((const float4*)(Opart + 2097152))[idx];
  const float inv = 1.f / (lbuf[row] + lbuf[32768 + row]);
  float4 o;
  o.x = (o0.x + o1.x) * inv;
  o.y = (o0.y + o1.y) * inv;
  o.z = (o0.z + o1.z) * inv;
  o.w = (o0.w + o1.w) * inv;
  ((float4*)out)[idx] = o;
}

extern "C" void kernel_launch(void* const* d_in, const int* in_sizes, int n_in,
                              void* d_out, int out_size, void* d_ws, size_t ws_size,
                              hipStream_t stream) {
  // inputs: 0=x, 1=w_q(unused), 2=b_q(unused), 3=w_k, 4=b_k, 5=w_v, 6=b_v (fp32)
  const float* x  = (const float*)d_in[0];
  const float* wk = (const float*)d_in[3];
  const float* bk = (const float*)d_in[4];
  const float* wv = (const float*)d_in[5];
  const float* bv = (const float*)d_in[6];

  u16* ws   = (u16*)d_ws;
  u16* wbf  = ws;                             // 512 KB
  u16* Kmat = ws + 262144;                    // 4 MB
  u16* Vmat = Kmat + (size_t)16384 * 128;     // 4 MB
  u16* VTm  = Vmat + (size_t)16384 * 128;     // 4 MB
  float* Opart = (float*)(VTm + (size_t)16384 * 128);  // 2 x 8 MB
  float* lbuf  = Opart + 2 * 2097152;                  // 2 x 128 KB
  const bool split = ws_size >= (size_t)30200000;

  wconv_kernel<<<128, 256, 0, stream>>>(wk, wv, wbf);
  kv_gemm_kernel<<<256, 512, 0, stream>>>(x, wbf, bk, bv, Kmat, Vmat, VTm);
  if (split) {
    flash_kernel<<<dim3(64, 8, 2), 128, 0, stream>>>(Kmat, Vmat, VTm,
                                                     (float*)d_out, Opart, lbuf);
    combine_kernel<<<2048, 256, 0, stream>>>(Opart, lbuf, (float*)d_out);
  } else {
    flash_kernel<<<dim3(64, 8, 1), 128, 0, stream>>>(Kmat, Vmat, VTm,
                                                     (float*)d_out, Opart, lbuf);
  }
}

// Round 8
// 164.519 us; speedup vs baseline: 1.1691x; 1.1691x over previous
//
#include <hip/hip_runtime.h>
#include <hip/hip_bf16.h>

// B=8, N=2048, DX=1024, DK=DV=128. Inputs fp32, output fp32.
// out = softmax(K V^T / sqrt(128)) V, K = x Wk^T + bk, V = x Wv^T + bv.
// R16: flash = R13 geometry (64q/4 waves/KVBLK=64, counted vmcnt(8)) with the
//      sP LDS round-trip replaced by swapped-operand QK (S^T = mfma(V,K), lane
//      holds P-row for q=l16) + in-register bf16 pack + 16 bpermute transpose
//      into PV A-frags (T12-adapted). kv_gemm/wconv/combine = R13 (verified).

typedef short s16x8 __attribute__((ext_vector_type(8)));
typedef float f32x4 __attribute__((ext_vector_type(4)));
typedef unsigned short u16;

#define AS1 __attribute__((address_space(1)))
#define AS3 __attribute__((address_space(3)))

__device__ __forceinline__ void gld_lds16(const void* g, void* l) {
  // async global->LDS: per-lane gather, lands at wave-uniform base + lane*16
  __builtin_amdgcn_global_load_lds((const AS1 unsigned int*)g, (AS3 unsigned int*)l, 16, 0, 0);
}

__device__ __forceinline__ float bf2f(u16 u) {
  unsigned int v = ((unsigned int)u) << 16;
  return __builtin_bit_cast(float, v);
}
__device__ __forceinline__ u16 f2bf(float f) {
  unsigned int u = __builtin_bit_cast(unsigned int, f);
  u += 0x7fffu + ((u >> 16) & 1u);   // RNE
  return (u16)(u >> 16);
}
__device__ __forceinline__ unsigned pack_bf2(float a, float b) {
  unsigned ua = __builtin_bit_cast(unsigned, a) + 0x8000u;
  unsigned ub = __builtin_bit_cast(unsigned, b) + 0x8000u;
  return __builtin_amdgcn_perm(ub, ua, 0x07060302u);   // lo=bf16(a), hi=bf16(b)
}

// ---------------- Kernel W: weights fp32 -> bf16 (wk||wv -> wbf[256][1024]) --
__global__ __launch_bounds__(256, 4) void wconv_kernel(
    const float* __restrict__ wk, const float* __restrict__ wv,
    u16* __restrict__ wbf)
{
  const int e = (blockIdx.x * 256 + threadIdx.x) * 8;
  const float* src = (e < 131072) ? (wk + e) : (wv + (e - 131072));
  float4 a = *(const float4*)src;
  float4 b = *(const float4*)(src + 4);
  union { unsigned u[4]; s16x8 v; } pk;
  pk.u[0] = pack_bf2(a.x, a.y); pk.u[1] = pack_bf2(a.z, a.w);
  pk.u[2] = pack_bf2(b.x, b.y); pk.u[3] = pack_bf2(b.z, b.w);
  *(s16x8*)(wbf + e) = pk.v;
}

// ---------------- Kernel A: fused K|V projection GEMM (+ V^T emit) -----------
// grid 256, 512 threads: block = 64 rows x 256 cols. BK=64, 16 steps.
// Wave w: rows (w>>2)*32..+31, cols (w&3)*64..+63 (w&3 0-1: K, 2-3: V).
// B prefetch 2 steps deep into 4 LDS buffers; raw barrier + vmcnt(6) so
// in-flight DMAs are never drained at the barrier. A regs 2 steps deep.
// K output pre-scaled by 1/sqrt(128) so flash softmax is __expf(sacc).
__global__ __launch_bounds__(512, 2) void kv_gemm_kernel(
    const float* __restrict__ x, const u16* __restrict__ wbf,
    const float* __restrict__ bk, const float* __restrict__ bv,
    u16* __restrict__ Kout, u16* __restrict__ Vout, u16* __restrict__ VTout)
{
  __shared__ u16 sA[2][8 * 512];     // 2 x 8 KB  [slice=grb*2+ks][lane][8]
  __shared__ u16 sB[4][32 * 512];    // 4 x 32 KB [slice=gcb*2+ks][lane][8]

  const int tid  = threadIdx.x;
  const int wave = tid >> 6;
  const int lane = tid & 63;
  const int l16  = lane & 15;
  const int lq   = lane >> 4;
  const int row0 = blockIdx.x * 64;
  const int wr   = wave >> 2;        // row half 0..1
  const int wc   = wave & 3;         // col group 0..3

  f32x4 acc[2][4];
  for (int i = 0; i < 2; ++i)
    for (int j = 0; j < 4; ++j) acc[i][j] = (f32x4){0.f, 0.f, 0.f, 0.f};

  // A: thread stages chunk: kc=tid&7 (k-chunk of 8 floats), arow=tid>>3 (0..63)
  const int kc = tid & 7, arow = tid >> 3;
  const float* aSrc = x + (size_t)(row0 + arow) * 1024 + kc * 8;
  const int aSlot = (((arow >> 4) * 2 + (kc >> 2)) * 512) + ((kc & 3) * 16 + (arow & 15)) * 8;

  // B: 4 chunks/thread; chunk i -> slice sl = wave + i*8 (gcb=sl>>1, ks=sl&1)
  const u16* bSrc[4];
  for (int i = 0; i < 4; ++i) {
    const int sl = wave + i * 8;
    bSrc[i] = wbf + (size_t)((sl >> 1) * 16 + l16) * 1024 + (sl & 1) * 32 + lq * 8;
  }

  // prologue: B(0)->buf0, B(1)->buf1 in flight; A regs 2 steps deep
  for (int i = 0; i < 4; ++i)
    gld_lds16(bSrc[i], &sB[0][(wave + i * 8) * 512]);
  float4 p0a = *(const float4*)(aSrc);
  float4 p0b = *(const float4*)(aSrc + 4);
  for (int i = 0; i < 4; ++i)
    gld_lds16(bSrc[i] + 64, &sB[1][(wave + i * 8) * 512]);
  float4 p1a = *(const float4*)(aSrc + 64);
  float4 p1b = *(const float4*)(aSrc + 68);

#pragma unroll
  for (int s = 0; s < 16; ++s) {
    const int buf2 = s & 1, buf4 = s & 3;
    // pack A(s) -> sA[buf2]  (reg dep makes compiler wait for A(s) loads)
    {
      union { unsigned u[4]; s16x8 v; } pk;
      pk.u[0] = pack_bf2(p0a.x, p0a.y); pk.u[1] = pack_bf2(p0a.z, p0a.w);
      pk.u[2] = pack_bf2(p0b.x, p0b.y); pk.u[3] = pack_bf2(p0b.z, p0b.w);
      *(s16x8*)(&sA[buf2][aSlot]) = pk.v;
    }
    asm volatile("s_waitcnt lgkmcnt(0)" ::: "memory");  // own LDS writes visible
    __builtin_amdgcn_s_barrier();
    // counted drain: each iter issues exactly 6 VMEM (4 gld_lds + 2 A-loads),
    // so vmcnt(6) retires everything from iter s-2 and older => B(s) landed,
    // while B(s+1)+A(s+1) stay in flight across the barrier. Last iter: 0.
    if (s == 15) asm volatile("s_waitcnt vmcnt(0)" ::: "memory");
    else         asm volatile("s_waitcnt vmcnt(6)" ::: "memory");
    __builtin_amdgcn_sched_barrier(0);

    if (s + 2 < 16) {   // B(s+2) flies for the next two compute phases
      for (int i = 0; i < 4; ++i)
        gld_lds16(bSrc[i] + (s + 2) * 64, &sB[(s + 2) & 3][(wave + i * 8) * 512]);
    }
    // rotate A pipeline: consume p0 (packed above), load A(s+2)
    p0a = p1a; p0b = p1b;
    if (s + 2 < 16) {
      p1a = *(const float4*)(aSrc + (s + 2) * 64);
      p1b = *(const float4*)(aSrc + (s + 2) * 64 + 4);
    }

    s16x8 af[2][2], bfr[4][2];
    for (int rb = 0; rb < 2; ++rb)
      for (int ks = 0; ks < 2; ++ks)
        af[rb][ks] = *(const s16x8*)(&sA[buf2][(((wr * 2 + rb) * 2 + ks) * 64 + lane) * 8]);
    for (int cb = 0; cb < 4; ++cb)
      for (int ks = 0; ks < 2; ++ks)
        bfr[cb][ks] = *(const s16x8*)(&sB[buf4][(((wc * 4 + cb) * 2 + ks) * 64 + lane) * 8]);
    for (int rb = 0; rb < 2; ++rb)
      for (int cb = 0; cb < 4; ++cb)
        for (int ks = 0; ks < 2; ++ks)
          acc[rb][cb] = __builtin_amdgcn_mfma_f32_16x16x32_bf16(af[rb][ks], bfr[cb][ks], acc[rb][cb], 0, 0, 0);
  }

  const int  colBase = wc * 64;
  const bool isV = (wc >= 2);
  const float vscale = isV ? 1.0f : 0.08838834764831845f;   // 1/sqrt(128) folded into K
  u16* outN = isV ? Vout : Kout;
  float fbias[4];
  for (int cb = 0; cb < 4; ++cb) {
    const int col = colBase + cb * 16 + l16;
    fbias[cb] = isV ? bv[col - 128] : bk[col];
  }
  for (int rb = 0; rb < 2; ++rb) {
    const int grow0 = row0 + wr * 32 + rb * 16 + lq * 4;
    for (int cb = 0; cb < 4; ++cb) {
      const int gcol = colBase + cb * 16 + l16;
      const int ocol = isV ? (gcol - 128) : gcol;
      union { u16 u[4]; unsigned long long ull; } pk;
      for (int r = 0; r < 4; ++r) {
        u16 h = f2bf((acc[rb][cb][r] + fbias[cb]) * vscale);
        outN[(size_t)(grow0 + r) * 128 + ocol] = h;
        pk.u[r] = h;
      }
      if (isV) {
        const int bidx = grow0 >> 11;
        const int n    = grow0 & 2047;
        *(unsigned long long*)(VTout + (size_t)bidx * 128 * 2048 + (size_t)ocol * 2048 + n) = pk.ull;
      }
    }
  }
}

// ---------------- Kernel B: flash attention (swapped-QK, in-register P) ------
// grid (32, 8, nz): 64 q-rows/block; KV tiles of 64; single barrier/tile.
// S^T = mfma(V_frag, K_frag): lane (l16=q, lq) holds P[q][m = t*16+lq*4+r].
// P -> bf16 A-frags in-register: pack_bf2 pairs + 16 bpermute + 8 cndmask.
// Frag math: frag[ksm].dword[w] = D[2ksm+a][w&1] from lane (l16, g=2b+(w>>1)),
// where lq = 2a+b. Counted vmcnt(8) staging as R13 (verified).
__global__ __launch_bounds__(256, 2) void flash_kernel(
    const u16* __restrict__ Kmat, const u16* __restrict__ Vmat,
    const u16* __restrict__ VT, float* __restrict__ out,
    float* __restrict__ Opart, float* __restrict__ lbuf)
{
  __shared__ u16 sV[2][16 * 512];    // 2 x 16 KB  [t*4+ks][lane][8]
  __shared__ u16 sVT[2][16 * 512];   // 2 x 16 KB  [v*2+ksm][lane][8]

  const int tid  = threadIdx.x;
  const int wave = tid >> 6;
  const int lane = tid & 63;
  const int l16  = lane & 15;
  const int lq   = lane >> 4;
  const int b    = blockIdx.y;
  const int q0   = blockIdx.x * 64;
  const int z    = blockIdx.z;
  const int ntiles = (2048 / gridDim.z) / 64;
  const int mstart = z * (2048 / gridDim.z);

  const int bq   = lq & 1;                 // b of lq = 2a+b
  const bool ahi = (lq & 2) != 0;          // a
  const int src0 = l16 + (2 * bq + 0) * 16;
  const int src1 = l16 + (2 * bq + 1) * 16;

  // K fragments -> registers (pre-scaled by 1/sqrt(128) at projection)
  s16x8 kf[4];
  {
    const u16* Kb = Kmat + ((size_t)b * 2048 + q0 + wave * 16 + l16) * 128 + lq * 8;
    for (int ks = 0; ks < 4; ++ks) kf[ks] = *(const s16x8*)(Kb + ks * 32);
  }

  // staging bases: chunk i -> slice sl = wave + i*4
  const u16* vSrc[4];  const u16* vtSrc[4];
  {
    const u16* Vb  = Vmat + (size_t)b * 2048 * 128;
    const u16* VTb = VT   + (size_t)b * 128 * 2048;
    for (int i = 0; i < 4; ++i) {
      const int sl = wave + i * 4;
      vSrc[i]  = Vb  + (size_t)((sl >> 2) * 16 + l16) * 128 + (sl & 3) * 32 + lq * 8;  // + m0*128
      vtSrc[i] = VTb + (size_t)((sl >> 1) * 16 + l16) * 2048 + (sl & 1) * 32 + lq * 8; // + m0
    }
  }

  f32x4 oacc[8];
  for (int v = 0; v < 8; ++v) oacc[v] = (f32x4){0.f, 0.f, 0.f, 0.f};
  float lrow = 0.f;                        // denominator for q = l16 (partial)

  // prologue: stage tile 0 -> buf 0
  for (int i = 0; i < 4; ++i) {
    gld_lds16(vSrc[i] + (size_t)mstart * 128, &sV[0][(wave + i * 4) * 512]);
    gld_lds16(vtSrc[i] + mstart,              &sVT[0][(wave + i * 4) * 512]);
  }

  for (int mt = 0; mt < ntiles; ++mt) {
    const int buf = mt & 1;
    asm volatile("s_barrier" ::: "memory");    // all waves done reading buf^1
    if (mt + 1 < ntiles) {                     // issue stage(mt+1) FIRST...
      const int m1 = mstart + (mt + 1) * 64;
      for (int i = 0; i < 4; ++i) {
        gld_lds16(vSrc[i] + (size_t)m1 * 128, &sV[buf ^ 1][(wave + i * 4) * 512]);
        gld_lds16(vtSrc[i] + m1,              &sVT[buf ^ 1][(wave + i * 4) * 512]);
      }
      // ...then counted wait: 16 outstanding -> 8 => stage(mt) landed,
      // stage(mt+1)'s 8 stay in flight through this whole tile's compute.
      asm volatile("s_waitcnt vmcnt(8)" ::: "memory");
    } else {
      asm volatile("s_waitcnt vmcnt(0)" ::: "memory");
    }
    __builtin_amdgcn_sched_barrier(0);

    // S^T = V.K^T (swapped operands): sacc[t] col=l16=q, row=m=t*16+lq*4+r
    f32x4 sacc[4];
    for (int t = 0; t < 4; ++t) sacc[t] = (f32x4){0.f, 0.f, 0.f, 0.f};
    for (int ks = 0; ks < 4; ++ks)
      for (int t = 0; t < 4; ++t)
        sacc[t] = __builtin_amdgcn_mfma_f32_16x16x32_bf16(
            *(const s16x8*)(&sV[buf][(t * 4 + ks) * 512 + lane * 8]), kf[ks], sacc[t], 0, 0, 0);

    // softmax (no max-shift; scale pre-folded): p = exp(s); pack to bf16 pairs
    unsigned D[4][2];
    float rs = 0.f;
    for (int t = 0; t < 4; ++t)
      for (int p = 0; p < 2; ++p) {
        float e0 = __expf(sacc[t][2 * p]);
        float e1 = __expf(sacc[t][2 * p + 1]);
        unsigned d = pack_bf2(e0, e1);
        D[t][p] = d;
        rs += bf2f((u16)(d & 0xffffu)) + bf2f((u16)(d >> 16));  // sum matches numerator
      }
    lrow += rs;

    // transpose P into PV A-frags: 16 bpermute + 8 select (no LDS)
    s16x8 pa[2];
    for (int ksm = 0; ksm < 2; ++ksm) {
      union { unsigned u[4]; s16x8 v; } fr;
      {
        unsigned lo = __shfl((int)D[2 * ksm][0], src0);
        unsigned hi = __shfl((int)D[2 * ksm + 1][0], src0);
        fr.u[0] = ahi ? hi : lo;
      }
      {
        unsigned lo = __shfl((int)D[2 * ksm][1], src0);
        unsigned hi = __shfl((int)D[2 * ksm + 1][1], src0);
        fr.u[1] = ahi ? hi : lo;
      }
      {
        unsigned lo = __shfl((int)D[2 * ksm][0], src1);
        unsigned hi = __shfl((int)D[2 * ksm + 1][0], src1);
        fr.u[2] = ahi ? hi : lo;
      }
      {
        unsigned lo = __shfl((int)D[2 * ksm][1], src1);
        unsigned hi = __shfl((int)D[2 * ksm + 1][1], src1);
        fr.u[3] = ahi ? hi : lo;
      }
      pa[ksm] = fr.v;
    }

    // O += P.V : A=pa (row=q), B=sVT frag (col=d); C layout same as R13
    for (int ksm = 0; ksm < 2; ++ksm)
      for (int v = 0; v < 8; ++v)
        oacc[v] = __builtin_amdgcn_mfma_f32_16x16x32_bf16(
            pa[ksm], *(const s16x8*)(&sVT[buf][(v * 2 + ksm) * 512 + lane * 8]), oacc[v], 0, 0, 0);
  }

  // finish l: lane holds partial for q=l16; sum across the 4 lq replicas
  lrow += __shfl_xor(lrow, 16);
  lrow += __shfl_xor(lrow, 32);
  // now every lane has l[q = l16] (q relative to this wave's 16 rows)

  const size_t rowg = (size_t)b * 2048 + q0 + wave * 16;
  if (gridDim.z == 1) {
    for (int r = 0; r < 4; ++r) {
      const float inv = 1.f / __shfl(lrow, lq * 4 + r);   // l for out-row q=lq*4+r
      for (int v = 0; v < 8; ++v)
        out[(rowg + lq * 4 + r) * 128 + v * 16 + l16] = oacc[v][r] * inv;
    }
  } else {
    float* Op = Opart + (size_t)z * 2097152;
    float* lp = lbuf + (size_t)z * 32768;
    for (int r = 0; r < 4; ++r)
      for (int v = 0; v < 8; ++v)
        Op[(rowg + lq * 4 + r) * 128 + v * 16 + l16] = oacc[v][r];
    if (lq == 0)
      lp[rowg + l16] = lrow;
  }
}

// ---------------- Kernel C: combine 2 KV-split partials ----------------------
__global__ __launch_bounds__(256, 4) void combine_kernel(
    const float* __restrict__ Opart, const float* __restrict__ lbuf,
    float* __restrict__ out)
{
  const int idx = blockIdx.x * 256 + threadIdx.x;    // float4 idx, 524288 total
  const int row = idx >> 5;
  const float4 o0 = ((const float4*)Opart)[idx];
  const float4 o1 = ((const float4*)(Opart + 2097152))[idx];
  const float inv = 1.f / (lbuf[row] + lbuf[32768 + row]);
  float4 o;
  o.x = (o0.x + o1.x) * inv;
  o.y = (o0.y + o1.y) * inv;
  o.z = (o0.z + o1.z) * inv;
  o.w = (o0.w + o1.w) * inv;
  ((float4*)out)[idx] = o;
}

extern "C" void kernel_launch(void* const* d_in, const int* in_sizes, int n_in,
                              void* d_out, int out_size, void* d_ws, size_t ws_size,
                              hipStream_t stream) {
  // inputs: 0=x, 1=w_q(unused), 2=b_q(unused), 3=w_k, 4=b_k, 5=w_v, 6=b_v (fp32)
  const float* x  = (const float*)d_in[0];
  const float* wk = (const float*)d_in[3];
  const float* bk = (const float*)d_in[4];
  const float* wv = (const float*)d_in[5];
  const float* bv = (const float*)d_in[6];

  u16* ws   = (u16*)d_ws;
  u16* wbf  = ws;                             // 512 KB
  u16* Kmat = ws + 262144;                    // 4 MB
  u16* Vmat = Kmat + (size_t)16384 * 128;     // 4 MB
  u16* VTm  = Vmat + (size_t)16384 * 128;     // 4 MB
  float* Opart = (float*)(VTm + (size_t)16384 * 128);  // 2 x 8 MB
  float* lbuf  = Opart + 2 * 2097152;                  // 2 x 128 KB
  const bool split = ws_size >= (size_t)30200000;

  wconv_kernel<<<128, 256, 0, stream>>>(wk, wv, wbf);
  kv_gemm_kernel<<<256, 512, 0, stream>>>(x, wbf, bk, bv, Kmat, Vmat, VTm);
  if (split) {
    flash_kernel<<<dim3(32, 8, 2), 256, 0, stream>>>(Kmat, Vmat, VTm,
                                                     (float*)d_out, Opart, lbuf);
    combine_kernel<<<2048, 256, 0, stream>>>(Opart, lbuf, (float*)d_out);
  } else {
    flash_kernel<<<dim3(32, 8, 1), 256, 0, stream>>>(Kmat, Vmat, VTm,
                                                     (float*)d_out, Opart, lbuf);
  }
}